// Round 1
// baseline (44.270 us; speedup 1.0000x reference)
//
#include <hip/hip_runtime.h>

// Problem constants (fixed by setup_inputs): lfi [B,A,H,W,C], f_maps [B,H,W,F]
#define BB 4
#define AA 9
#define HH 256
#define WW 256
#define CC 9
#define FF 64

// ---------------------------------------------------------------------------
// Kernel 1: hv[b,w,f] = mean over h of f_maps[b,h,w,f]
// Block per (b,w): 256 threads = 4 h-lanes (hl) x 64 f. Each wave reads a
// contiguous 256B span (f=0..63) per h step; LDS-reduce across the 4 hl.
// ---------------------------------------------------------------------------
__global__ __launch_bounds__(256) void k_hv(const float* __restrict__ fm,
                                            float* __restrict__ hv) {
    const int blk = blockIdx.x;       // b*WW + w
    const int b = blk >> 8;           // WW == 256
    const int w = blk & 255;
    const int f = threadIdx.x & 63;
    const int hl = threadIdx.x >> 6;  // 0..3

    const float* base = fm + (((size_t)b * HH) * WW + w) * FF + f;
    float s = 0.f;
#pragma unroll 8
    for (int h = hl; h < HH; h += 4) {
        s += base[(size_t)h * WW * FF];
    }
    __shared__ float sm[256];
    sm[threadIdx.x] = s;
    __syncthreads();
    if (hl == 0) {
        float t = sm[f] + sm[64 + f] + sm[128 + f] + sm[192 + f];
        hv[(size_t)blk * FF + f] = t * (1.0f / HH);
    }
}

// ---------------------------------------------------------------------------
// Kernel 2: inv[b,f] = 1 / max over w of hv[b,w,f]
// Block per (b,f): 64 lanes, each covers 4 w values, then shuffle-max.
// ---------------------------------------------------------------------------
__global__ __launch_bounds__(64) void k_inv(const float* __restrict__ hv,
                                            float* __restrict__ inv) {
    const int b = blockIdx.x >> 6;
    const int f = blockIdx.x & 63;
    const int t = threadIdx.x;
    float mx = -1e30f;
#pragma unroll
    for (int j = 0; j < 4; ++j) {
        mx = fmaxf(mx, hv[((size_t)b * WW + (t + 64 * j)) * FF + f]);
    }
#pragma unroll
    for (int off = 32; off; off >>= 1)
        mx = fmaxf(mx, __shfl_xor(mx, off));
    if (t == 0) inv[blockIdx.x] = 1.0f / mx;
}

// ---------------------------------------------------------------------------
// Kernel 3: m[b,h,w] = mean over (a,c) of lfi[b,a,h,w,c]
// One thread per (b,h,w). 81 loads fully unrolled; per a-iteration the wave
// reads a contiguous 64*9*4 = 2304B span.
// ---------------------------------------------------------------------------
__global__ __launch_bounds__(256) void k_m(const float* __restrict__ lfi,
                                           float* __restrict__ m) {
    const int gid = blockIdx.x * 256 + threadIdx.x;  // b*HH*WW + h*WW + w
    const int b = gid >> 16;                         // HH*WW == 65536
    const int hw = gid & 65535;

    const size_t astride = (size_t)HH * WW * CC;  // 589824
    const float* base = lfi + (size_t)b * AA * astride + (size_t)hw * CC;

    float s = 0.f;
#pragma unroll
    for (int a = 0; a < AA; ++a) {
        const float* p = base + (size_t)a * astride;
#pragma unroll
        for (int c = 0; c < CC; ++c) s += p[c];
    }
    m[gid] = s * (1.0f / (AA * CC));
}

// ---------------------------------------------------------------------------
// Kernel 4: out[b,h,w,f] = m[b,h,w] * hv[b,h,f] * inv[b,f]
// One thread per float4 along f. Stores 16B/lane contiguous.
// ---------------------------------------------------------------------------
__global__ __launch_bounds__(256) void k_out(const float* __restrict__ m,
                                             const float* __restrict__ hv,
                                             const float* __restrict__ inv,
                                             float4* __restrict__ out) {
    const int idx = blockIdx.x * 256 + threadIdx.x;  // over B*H*W*F/4
    const int f4 = idx & 15;                         // FF/4 == 16
    const int rest = idx >> 4;                       // b*HH*WW + h*WW + w
    const int h = (rest >> 8) & 255;
    const int b = rest >> 16;

    const float mv = m[rest];
    const float4 hv4 = ((const float4*)hv)[((size_t)(b * HH + h)) * (FF / 4) + f4];
    const float4 iv4 = ((const float4*)inv)[b * (FF / 4) + f4];

    float4 o;
    o.x = mv * hv4.x * iv4.x;
    o.y = mv * hv4.y * iv4.y;
    o.z = mv * hv4.z * iv4.z;
    o.w = mv * hv4.w * iv4.w;
    out[idx] = o;
}

extern "C" void kernel_launch(void* const* d_in, const int* in_sizes, int n_in,
                              void* d_out, int out_size, void* d_ws, size_t ws_size,
                              hipStream_t stream) {
    const float* lfi = (const float*)d_in[0];     // [B,A,H,W,C] f32
    const float* fm  = (const float*)d_in[1];     // [B,H,W,F]   f32
    float* out = (float*)d_out;                   // [B,H,W,F]   f32

    // Workspace layout
    char* ws = (char*)d_ws;
    float* hv  = (float*)ws;                                  // B*W*F   = 65536 f
    float* inv = (float*)(ws + (size_t)BB * WW * FF * 4);     // B*F     = 256 f
    float* m   = (float*)(ws + (size_t)BB * WW * FF * 4 + 1024); // B*H*W = 262144 f

    // 1) hv (column means of f_maps)
    k_hv<<<BB * WW, 256, 0, stream>>>(fm, hv);
    // 2) inv (per (b,f) reciprocal of max over w)
    k_inv<<<BB * FF, 64, 0, stream>>>(hv, inv);
    // 3) m (angular mean of lfi)
    k_m<<<(BB * HH * WW) / 256, 256, 0, stream>>>(lfi, m);
    // 4) out
    k_out<<<(BB * HH * WW * FF / 4) / 256, 256, 0, stream>>>(m, hv, inv, (float4*)out);
}